// Round 3
// baseline (115.360 us; speedup 1.0000x reference)
//
#include <hip/hip_runtime.h>

// B=256, C=2048, H*W=128, NUM_CLASSES=10000
// Outputs (fp32, concat): logits[256*10000], logits[256*10000],
//                         neck_feat[256*2048], new_weight[256] (== 1.0 analytically)
// targets are dead.

#define OUT1_OFF (256 * 10000)
#define FEAT_OFF (2 * 256 * 10000)
#define NW_OFF   (2 * 256 * 10000 + 256 * 2048)

typedef __attribute__((ext_vector_type(4))) float f32x4;
typedef __attribute__((ext_vector_type(8))) short bf16x8;
typedef __attribute__((ext_vector_type(4))) unsigned int u32x4;

__device__ inline unsigned pk2bf(float lo, float hi) {
    unsigned a = __float_as_uint(lo), b = __float_as_uint(hi);
    unsigned ra = (a + 0x7FFFu + ((a >> 16) & 1u)) >> 16;
    unsigned rb = (b + 0x7FFFu + ((b >> 16) & 1u)) & 0xFFFF0000u;
    return ra | rb;
}

__device__ inline void gload_lds16(const void* g, void* l) {
    __builtin_amdgcn_global_load_lds(
        (const __attribute__((address_space(1))) void*)g,
        (__attribute__((address_space(3))) void*)l, 16, 0, 0);
}

// ---------------------------------------------------------------------------
// Kernel 1: mean over H*W=128 floats per (b,c) row. 2048 blocks x 256 thr,
// 8 iters; each 32-lane group reduces 4 consecutive rows per iter (4 loads
// in flight per lane). Writes feat fp32 (float4) + wsA bf16 fragment-major:
// elem (m=b,k=c) at chunk ((b>>4)*256 + (c>>3))*16 + (b&15), u32 word (c&7)>>1.
// ---------------------------------------------------------------------------
__global__ __launch_bounds__(256) void pool_kernel(
    const float* __restrict__ f, float* __restrict__ out,
    unsigned int* __restrict__ wsA32) {
    int tid = threadIdx.x;
    int g = tid >> 5;
    int l = tid & 31;
#pragma unroll
    for (int it = 0; it < 8; ++it) {
        int r0 = blockIdx.x * 256 + it * 32 + g * 4;  // rows r0..r0+3
        const f32x4* s0 = (const f32x4*)(f + (size_t)r0 * 128);
        f32x4 v0 = s0[l];
        f32x4 v1 = s0[l + 32];
        f32x4 v2 = s0[l + 64];
        f32x4 v3 = s0[l + 96];
        float a0 = v0[0] + v0[1] + v0[2] + v0[3];
        float a1 = v1[0] + v1[1] + v1[2] + v1[3];
        float a2 = v2[0] + v2[1] + v2[2] + v2[3];
        float a3 = v3[0] + v3[1] + v3[2] + v3[3];
#pragma unroll
        for (int off = 16; off >= 1; off >>= 1) {
            a0 += __shfl_xor(a0, off);
            a1 += __shfl_xor(a1, off);
            a2 += __shfl_xor(a2, off);
            a3 += __shfl_xor(a3, off);
        }
        if (l == 0) {
            float m0 = a0 * (1.0f / 128.0f), m1 = a1 * (1.0f / 128.0f);
            float m2 = a2 * (1.0f / 128.0f), m3 = a3 * (1.0f / 128.0f);
            f32x4 fv = {m0, m1, m2, m3};
            *(f32x4*)&out[FEAT_OFF + r0] = fv;
            int bb = r0 >> 11, c = r0 & 2047;  // c % 4 == 0
            int chunk = ((bb >> 4) * 256 + (c >> 3)) * 16 + (bb & 15);
            uint2 pw;
            pw.x = pk2bf(m0, m1);
            pw.y = pk2bf(m2, m3);
            *(uint2*)&wsA32[chunk * 4 + ((c & 7) >> 1)] = pw;
        }
    }
    if (blockIdx.x == 0) out[NW_OFF + tid] = 1.0f;
}

// ---------------------------------------------------------------------------
// Kernel 2: logits = A(256x2048 bf16) * W(10000x2048 fp32->bf16)^T
// BM=128, BN=64, BK=64. Grid (2,157) = 314 blocks -> 2 blocks/CU (72 KB LDS),
// all resident, 16 waves/CU. 512 threads = 8 waves (4m x 2n), wave tile 32x32
// (2x2 frags of 16x16x32). Triple-buffered LDS, depth-2 in flight, counted
// vmcnt(4), one s_barrier per K-step. A via global_load_lds (fragment-major
// ws -> linear LDS); B reg-staged fp32 -> bf16 (T14 issue-early/write-late).
// ---------------------------------------------------------------------------
__global__ __launch_bounds__(512) void gemm_kernel(
    const u32x4* __restrict__ A16, const float* __restrict__ W,
    float* __restrict__ out) {
    __shared__ u32x4 As[3][1024];  // 16 KB per buf
    __shared__ u32x4 Bs[3][512];   // 8 KB per buf -> 72 KB total

    int tid = threadIdx.x;
    int mhalf = blockIdx.x;      // 0..1
    int n0 = blockIdx.y * 64;    // 0..156
    int wid = tid >> 6, lane = tid & 63;
    int wm = wid >> 1, wn = wid & 1;
    int r = lane & 15, kqu = lane >> 4;

    // A staging: 2 chunks/thread, LDS ci = tid + i*512 (wave-linear);
    // global chunk = ((mhalf*8 + mf)*256 + kt*8 + kc)*16 + rr
    const u32x4* ga[2];
#pragma unroll
    for (int i = 0; i < 2; ++i) {
        int ci = tid + i * 512;
        ga[i] = A16 + (((mhalf * 8 + (ci >> 7)) * 256 + ((ci >> 4) & 7)) * 16 + (ci & 15));
    }
    // B staging: thread tid -> chunk ci=tid: row nr, 8 k-elems at kg*8
    int nr = n0 + (((tid >> 7) << 4) | (tid & 15));
    if (nr > 9999) nr = 9999;  // clamp; stores predicated
    int kg = (tid >> 4) & 7;
    const f32x4* gb = (const f32x4*)(W + (size_t)nr * 2048 + kg * 8);

    f32x4 acc[2][2];
#pragma unroll
    for (int i = 0; i < 2; ++i)
#pragma unroll
        for (int j = 0; j < 2; ++j) acc[i][j] = (f32x4){0.f, 0.f, 0.f, 0.f};

    f32x4 rbA0, rbA1, rbB0, rbB1;

#define STAGE_A(kt, buf)                                              \
    {                                                                 \
        _Pragma("unroll") for (int i = 0; i < 2; ++i)                 \
            gload_lds16(ga[i] + (kt) * 128, &As[buf][tid + i * 512]); \
    }
#define LOAD_B(kt, r0_, r1_)     \
    {                            \
        r0_ = gb[(kt) * 16];     \
        r1_ = gb[(kt) * 16 + 1]; \
    }
#define PACK_B(buf, r0_, r1_)            \
    {                                    \
        u32x4 p;                         \
        p.x = pk2bf(r0_[0], r0_[1]);     \
        p.y = pk2bf(r0_[2], r0_[3]);     \
        p.z = pk2bf(r1_[0], r1_[1]);     \
        p.w = pk2bf(r1_[2], r1_[3]);     \
        Bs[buf][tid] = p;                \
    }

    // ---- prologue: tiles 0 and 1 in flight ----
    STAGE_A(0, 0); LOAD_B(0, rbA0, rbA1);
    STAGE_A(1, 1); LOAD_B(1, rbB0, rbB1);
    asm volatile("s_waitcnt vmcnt(4)" ::: "memory");  // tile 0 landed
    __builtin_amdgcn_sched_barrier(0);
    PACK_B(0, rbA0, rbA1);
    asm volatile("s_waitcnt lgkmcnt(0)" ::: "memory");
    __builtin_amdgcn_sched_barrier(0);
    __builtin_amdgcn_s_barrier();
    __builtin_amdgcn_sched_barrier(0);

    for (int kt = 0; kt < 32; ++kt) {
        int cur = kt % 3;
        // issue tile kt+2 (A -> LDS DMA, B -> regs)
        if (kt <= 29) {
            int nx2 = (kt + 2) % 3;
            STAGE_A(kt + 2, nx2);
            if (kt & 1) { LOAD_B(kt + 2, rbB0, rbB1); }
            else        { LOAD_B(kt + 2, rbA0, rbA1); }
        }
        // compute tile kt
#pragma unroll
        for (int ks = 0; ks < 2; ++ks) {
            int kcl = ks * 4 + kqu;
            bf16x8 av[2], bv[2];
#pragma unroll
            for (int i = 0; i < 2; ++i)
                av[i] = *(const bf16x8*)&As[cur][(wm * 2 + i) * 128 + kcl * 16 + r];
#pragma unroll
            for (int j = 0; j < 2; ++j)
                bv[j] = *(const bf16x8*)&Bs[cur][(wn * 2 + j) * 128 + kcl * 16 + r];
#pragma unroll
            for (int i = 0; i < 2; ++i)
#pragma unroll
                for (int j = 0; j < 2; ++j)
                    acc[i][j] = __builtin_amdgcn_mfma_f32_16x16x32_bf16(
                        av[i], bv[j], acc[i][j], 0, 0, 0);
        }
        // wait tile kt+1 landed (the 4 newest vm ops are tile kt+2's)
        if (kt <= 29) { asm volatile("s_waitcnt vmcnt(4)" ::: "memory"); }
        else          { asm volatile("s_waitcnt vmcnt(0)" ::: "memory"); }
        __builtin_amdgcn_sched_barrier(0);
        if (kt <= 30) {
            int nx1 = (kt + 1) % 3;
            if (kt & 1) { PACK_B(nx1, rbA0, rbA1); }
            else        { PACK_B(nx1, rbB0, rbB1); }
            asm volatile("s_waitcnt lgkmcnt(0)" ::: "memory");
            __builtin_amdgcn_sched_barrier(0);
            __builtin_amdgcn_s_barrier();  // tile kt+1 ready for everyone
        }
        __builtin_amdgcn_sched_barrier(0);
    }

    // ---- epilogue: C and C*SCALE (SCALE=1) ----
#pragma unroll
    for (int i = 0; i < 2; ++i)
#pragma unroll
        for (int j = 0; j < 2; ++j) {
            int n = n0 + (wn * 2 + j) * 16 + r;
            if (n < 10000) {
                int mbase = mhalf * 128 + (wm * 2 + i) * 16 + kqu * 4;
#pragma unroll
                for (int q = 0; q < 4; ++q) {
                    float v = acc[i][j][q];
                    size_t off = (size_t)(mbase + q) * 10000 + n;
                    out[off] = v;
                    out[OUT1_OFF + off] = v;
                }
            }
        }
#undef STAGE_A
#undef LOAD_B
#undef PACK_B
}

extern "C" void kernel_launch(void* const* d_in, const int* in_sizes, int n_in,
                              void* d_out, int out_size, void* d_ws, size_t ws_size,
                              hipStream_t stream) {
    const float* feats = (const float*)d_in[0];
    // d_in[1] = targets (int32) — dead (new_weight == ones analytically)
    const float* weight = (const float*)d_in[2];
    float* out = (float*)d_out;

    pool_kernel<<<2048, 256, 0, stream>>>(feats, out, (unsigned int*)d_ws);
    gemm_kernel<<<dim3(2, 157), 512, 0, stream>>>((const u32x4*)d_ws, weight, out);
}

// Round 4
// 114.555 us; speedup vs baseline: 1.0070x; 1.0070x over previous
//
#include <hip/hip_runtime.h>

// B=256, C=2048, H*W=128, NUM_CLASSES=10000
// Outputs (fp32, concat): logits[256*10000], logits[256*10000],
//                         neck_feat[256*2048], new_weight[256] (== 1.0 analytically)
// targets are dead.

#define OUT1_OFF (256 * 10000)
#define FEAT_OFF (2 * 256 * 10000)
#define NW_OFF   (2 * 256 * 10000 + 256 * 2048)

typedef __attribute__((ext_vector_type(4))) float f32x4;
typedef __attribute__((ext_vector_type(8))) short bf16x8;
typedef __attribute__((ext_vector_type(4))) unsigned int u32x4;

__device__ inline unsigned pk2bf(float lo, float hi) {
    unsigned a = __float_as_uint(lo), b = __float_as_uint(hi);
    unsigned ra = (a + 0x7FFFu + ((a >> 16) & 1u)) >> 16;
    unsigned rb = (b + 0x7FFFu + ((b >> 16) & 1u)) & 0xFFFF0000u;
    return ra | rb;
}

__device__ inline void gload_lds16(const void* g, void* l) {
    __builtin_amdgcn_global_load_lds(
        (const __attribute__((address_space(1))) void*)g,
        (__attribute__((address_space(3))) void*)l, 16, 0, 0);
}

// ---------------------------------------------------------------------------
// Kernel 1 (pool): mean over 128 floats per row. 2048 blocks x 256 thr =
// 8192 waves = exactly 32 waves/CU (one residency round). Each 8-lane
// subgroup owns one row: 4 x f32x4 loads/lane (512B row), 3-level shfl_xor
// reduce. 8 rows/wave/iter, 8 iters. feat: 8 lanes store 32B run. wsA bf16
// fragment-major: rows r0..r0+7 (same b, c 8-aligned) = one 16B chunk,
// written by lanes 0-3 as 4 consecutive dwords.
// chunk(b,c) = ((b>>4)*256 + (c>>3))*16 + (b&15), word j = (c&7)>>1.
// ---------------------------------------------------------------------------
__global__ __launch_bounds__(256) void pool_kernel(
    const float* __restrict__ f, float* __restrict__ out,
    unsigned int* __restrict__ wsA32) {
    int tid = threadIdx.x;
    int w = tid >> 6, lane = tid & 63;
    int s = lane >> 3, il = lane & 7;
    int rbase = (blockIdx.x * 4 + w) * 64;
#pragma unroll
    for (int it = 0; it < 8; ++it) {
        int r = rbase + it * 8 + s;
        const f32x4* p = (const f32x4*)(f + (size_t)r * 128) + il;
        f32x4 a = p[0], b = p[8], c = p[16], d = p[24];
        float sum = ((a[0] + a[1]) + (a[2] + a[3])) + ((b[0] + b[1]) + (b[2] + b[3])) +
                    ((c[0] + c[1]) + (c[2] + c[3])) + ((d[0] + d[1]) + (d[2] + d[3]));
#pragma unroll
        for (int off = 1; off <= 4; off <<= 1) sum += __shfl_xor(sum, off);
        float mean = sum * (1.0f / 128.0f);
        if (il == 0) out[FEAT_OFF + r] = mean;  // 8 lanes -> one 32B run
        // gather pairs: lane l gets means of rows r0+2*(l&3), r0+2*(l&3)+1
        float u = __shfl(mean, ((lane & 3) * 2) * 8);
        float v = __shfl(mean, ((lane & 3) * 2 + 1) * 8);
        unsigned pw = pk2bf(u, v);
        int r0 = rbase + it * 8;
        int bb = r0 >> 11, cc = r0 & 2047;
        int chunk = ((bb >> 4) * 256 + (cc >> 3)) * 16 + (bb & 15);
        if (lane < 4) wsA32[chunk * 4 + lane] = pw;  // one 16B run
    }
    if (blockIdx.x == 0 && tid < 256) out[NW_OFF + tid] = 1.0f;
}

// ---------------------------------------------------------------------------
// Kernel 2 (GEMM): byte-identical structure to round 2 (best measured).
// logits = A(256x2048 bf16) * W(10000x2048 fp32->bf16)^T
// BM=256 (all of M), BN=64, BK=64. 157 blocks x 512 thr (8 waves 4m x 2n,
// wave tile 64x32 = 4x2 frags). Triple-buffered LDS (120 KB), depth-2 in
// flight, counted vmcnt(6), one s_barrier per K-step. W read exactly once.
// ---------------------------------------------------------------------------
__global__ __launch_bounds__(512) void gemm_kernel(
    const u32x4* __restrict__ A16, const float* __restrict__ W,
    float* __restrict__ out) {
    __shared__ u32x4 As[3][2048];  // 32 KB per buf
    __shared__ u32x4 Bs[3][512];   // 8 KB per buf  -> 120 KB total

    int tid = threadIdx.x;
    int n0 = blockIdx.x * 64;
    int wid = tid >> 6, lane = tid & 63;
    int wm = wid >> 1, wn = wid & 1;
    int r = lane & 15, kqu = lane >> 4;

    const u32x4* ga[4];
#pragma unroll
    for (int i = 0; i < 4; ++i) {
        int ci = tid + i * 512;
        ga[i] = A16 + (((ci >> 7) * 256 + ((ci >> 4) & 7)) * 16 + (ci & 15));
    }
    int nr = n0 + (((tid >> 7) << 4) | (tid & 15));
    if (nr > 9999) nr = 9999;  // clamp; stores predicated
    int kg = (tid >> 4) & 7;
    const f32x4* gb = (const f32x4*)(W + (size_t)nr * 2048 + kg * 8);

    f32x4 acc[4][2];
#pragma unroll
    for (int i = 0; i < 4; ++i)
#pragma unroll
        for (int j = 0; j < 2; ++j) acc[i][j] = (f32x4){0.f, 0.f, 0.f, 0.f};

    f32x4 rbA0, rbA1, rbB0, rbB1;

#define STAGE_A(kt, buf)                                              \
    {                                                                 \
        _Pragma("unroll") for (int i = 0; i < 4; ++i)                 \
            gload_lds16(ga[i] + (kt) * 128, &As[buf][tid + i * 512]); \
    }
#define LOAD_B(kt, r0_, r1_)     \
    {                            \
        r0_ = gb[(kt) * 16];     \
        r1_ = gb[(kt) * 16 + 1]; \
    }
#define PACK_B(buf, r0_, r1_)        \
    {                                \
        u32x4 p;                     \
        p.x = pk2bf(r0_[0], r0_[1]); \
        p.y = pk2bf(r0_[2], r0_[3]); \
        p.z = pk2bf(r1_[0], r1_[1]); \
        p.w = pk2bf(r1_[2], r1_[3]); \
        Bs[buf][tid] = p;            \
    }

    // ---- prologue: tiles 0 and 1 in flight ----
    STAGE_A(0, 0); LOAD_B(0, rbA0, rbA1);
    STAGE_A(1, 1); LOAD_B(1, rbB0, rbB1);
    asm volatile("s_waitcnt vmcnt(6)" ::: "memory");  // tile 0 landed
    __builtin_amdgcn_sched_barrier(0);
    PACK_B(0, rbA0, rbA1);
    asm volatile("s_waitcnt lgkmcnt(0)" ::: "memory");
    __builtin_amdgcn_sched_barrier(0);
    __builtin_amdgcn_s_barrier();
    __builtin_amdgcn_sched_barrier(0);

    for (int kt = 0; kt < 32; ++kt) {
        int cur = kt % 3;
        if (kt <= 29) {
            int nx2 = (kt + 2) % 3;
            STAGE_A(kt + 2, nx2);
            if (kt & 1) { LOAD_B(kt + 2, rbB0, rbB1); }
            else        { LOAD_B(kt + 2, rbA0, rbA1); }
        }
#pragma unroll
        for (int ks = 0; ks < 2; ++ks) {
            int kcl = ks * 4 + kqu;
            bf16x8 av[4], bv[2];
#pragma unroll
            for (int i = 0; i < 4; ++i)
                av[i] = *(const bf16x8*)&As[cur][(wm * 4 + i) * 128 + kcl * 16 + r];
#pragma unroll
            for (int j = 0; j < 2; ++j)
                bv[j] = *(const bf16x8*)&Bs[cur][(wn * 2 + j) * 128 + kcl * 16 + r];
#pragma unroll
            for (int i = 0; i < 4; ++i)
#pragma unroll
                for (int j = 0; j < 2; ++j)
                    acc[i][j] = __builtin_amdgcn_mfma_f32_16x16x32_bf16(
                        av[i], bv[j], acc[i][j], 0, 0, 0);
        }
        if (kt <= 29) { asm volatile("s_waitcnt vmcnt(6)" ::: "memory"); }
        else          { asm volatile("s_waitcnt vmcnt(0)" ::: "memory"); }
        __builtin_amdgcn_sched_barrier(0);
        if (kt <= 30) {
            int nx1 = (kt + 1) % 3;
            if (kt & 1) { PACK_B(nx1, rbA0, rbA1); }
            else        { PACK_B(nx1, rbB0, rbB1); }
            asm volatile("s_waitcnt lgkmcnt(0)" ::: "memory");
            __builtin_amdgcn_sched_barrier(0);
            __builtin_amdgcn_s_barrier();
        }
        __builtin_amdgcn_sched_barrier(0);
    }

    // ---- epilogue: C and C*SCALE (SCALE=1) ----
#pragma unroll
    for (int i = 0; i < 4; ++i)
#pragma unroll
        for (int j = 0; j < 2; ++j) {
            int n = n0 + (wn * 2 + j) * 16 + r;
            if (n < 10000) {
                int mbase = (wm * 4 + i) * 16 + kqu * 4;
#pragma unroll
                for (int q = 0; q < 4; ++q) {
                    float v = acc[i][j][q];
                    size_t off = (size_t)(mbase + q) * 10000 + n;
                    out[off] = v;
                    out[OUT1_OFF + off] = v;
                }
            }
        }
#undef STAGE_A
#undef LOAD_B
#undef PACK_B
}

extern "C" void kernel_launch(void* const* d_in, const int* in_sizes, int n_in,
                              void* d_out, int out_size, void* d_ws, size_t ws_size,
                              hipStream_t stream) {
    const float* feats = (const float*)d_in[0];
    // d_in[1] = targets (int32) — dead (new_weight == ones analytically)
    const float* weight = (const float*)d_in[2];
    float* out = (float*)d_out;

    pool_kernel<<<2048, 256, 0, stream>>>(feats, out, (unsigned int*)d_ws);
    gemm_kernel<<<157, 512, 0, stream>>>((const u32x4*)d_ws, weight, out);
}